// Round 5
// baseline (164.308 us; speedup 1.0000x reference)
//
#include <hip/hip_runtime.h>
#include <math.h>

#define NSHOT 5
#define WAY 32
#define DIM 640
#define NQ 4096
#define RNEAR 10

// ---- workspace layout (float offsets) ----
constexpr int OFF_PROTOS = 0;        // 32*640
constexpr int OFF_QPART  = 20480;    // 128*640 column partial sums
constexpr int OFF_C      = 102400;   // 32
constexpr int OFF_XVEC   = 102432;   // 32*640 (proto_p)
constexpr int OFF_G      = 122912;   // 32*4096 dot products
constexpr int OFF_S      = 253984;   // 32
constexpr int OFF_U      = 254016;   // 32
constexpr int OFF_NID    = 254048;   // 32*10
constexpr int OFF_TP     = 254368;   // 32*640 (test_proto)
constexpr int OFF_NIDX   = 274848;   // 32*10 ints
constexpr int OFF_CNT    = 275168;   // 32 ints (gemm2 tail counters)
constexpr int OFF_Q2D    = 275200;   // double[4096]
constexpr int OFF_X2D    = 283392;   // double[32]  (proto_p norms^2)
constexpr int OFF_X2D2   = 283456;   // double[32]  (test_proto norms^2)

__device__ __forceinline__ double wave_sum_d(double v) {
#pragma unroll
  for (int o = 32; o > 0; o >>= 1) v += __shfl_down(v, o, 64);
  return v;
}

__device__ __forceinline__ double dist_hyp(double c, double xdotq, double u2, double q2) {
  const double EPSd = 1e-5;
  double sc = sqrt(c);
  double nq = sqrt(q2);
  double nf = fmax(nq, EPSd);
  double th = tanh(sc * nf);
  double al = th / (sc * nf);
  double ny = fmax(al * nq, EPSd);
  double mx = 0.999 / sc;
  if (ny > mx) al *= mx / ny;
  double y2 = al * al * q2;
  double uy = -al * xdotq;
  double A = 1.0 + 2.0 * c * uy + c * y2;
  double B = 1.0 - c * u2;
  double den = fmax(1.0 + 2.0 * c * uy + c * c * u2 * y2, EPSd);
  double num2 = fmax(A * A * u2 + 2.0 * A * B * uy + B * B * y2, 0.0);
  double n = sqrt(num2) / den;
  double arg = sc * n;
  const double CLIP = (double)(1.0f - 1e-5f);
  arg = fmin(fmax(arg, 0.0), CLIP);
  return (1.0 / sc) * log((1.0 + arg) / (1.0 - arg));
}

// one pass over Q: per-row q2 (f64), per-block column partial sums, protos, zero G
__global__ __launch_bounds__(640) void k_fuse1(const float* __restrict__ Qm,
                                               const float* __restrict__ shot, float* ws) {
  __shared__ double q2w[32][10];
  int b = blockIdx.x, t = threadIdx.x;
  int lane = t & 63, wid = t >> 6;  // 10 waves
  if (b < WAY) {
    float s = 0.f;
#pragma unroll
    for (int s5 = 0; s5 < NSHOT; ++s5) s += shot[(size_t)(s5 * WAY + b) * DIM + t];
    ws[OFF_PROTOS + b * DIM + t] = s * 0.2f;
  }
  int r0 = b * 32;
  float colacc = 0.f;
  for (int r = 0; r < 32; ++r) {
    float v = Qm[(size_t)(r0 + r) * DIM + t];
    colacc += v;
    double sq = (double)v * v;
    sq = wave_sum_d(sq);
    if (lane == 0) q2w[r][wid] = sq;
  }
  ws[OFF_QPART + b * DIM + t] = colacc;
  __syncthreads();
  if (t < 32) {
    double s = 0.0;
#pragma unroll
    for (int k = 0; k < 10; ++k) s += q2w[t][k];
    ((double*)(ws + OFF_Q2D))[r0 + t] = s;
  }
  for (int j = b * 640 + t; j < WAY * NQ; j += 128 * 640) ws[OFF_G + j] = 0.0f;
}

// controller MLP, split-K, 512 threads; allmean from qpart partials inline
__global__ __launch_bounds__(512) void k_ctrl(const float* __restrict__ W1, const float* __restrict__ b1,
                                              const float* __restrict__ W2, const float* __restrict__ b2,
                                              const float* __restrict__ W3, const float* __restrict__ b3,
                                              float* ws) {
  __shared__ float pr[DIM], am[DIM];
  __shared__ float h1p[4][128], h1s[128];
  __shared__ float h2p[8][64], h2s[64];
  __shared__ float lg[5];
  __shared__ double redd[8];
  __shared__ double sBeta;
  int w = blockIdx.x, t = threadIdx.x;
  double ps = 0.0;
  for (int d = t; d < DIM; d += 512) {
    float v = ws[OFF_PROTOS + w * DIM + d];
    pr[d] = v; ps += (double)v * v;
    float qs_ = 0.f;
    for (int p = 0; p < 128; ++p) qs_ += ws[OFF_QPART + p * DIM + d];
    double s = (double)qs_;
    for (int w2 = 0; w2 < WAY; ++w2) s += 5.0 * (double)ws[OFF_PROTOS + w2 * DIM + d];
    am[d] = (float)(s / 4256.0);
  }
  ps = wave_sum_d(ps);
  int lane = t & 63, wid = t >> 6;
  if (lane == 0) redd[wid] = ps;
  __syncthreads();
  {
    int n = t & 127, s = t >> 7;
    float acc = 0.f;
    if (s < 2) {
      int k0 = s * 320;
#pragma unroll 8
      for (int k = 0; k < 320; ++k) acc = fmaf(pr[k0 + k], W1[(size_t)(k0 + k) * 128 + n], acc);
    } else {
      int k0 = (s - 2) * 320;
#pragma unroll 8
      for (int k = 0; k < 320; ++k) acc = fmaf(am[k0 + k], W1[(size_t)(640 + k0 + k) * 128 + n], acc);
    }
    h1p[s][n] = acc;
  }
  __syncthreads();
  if (t < 128) h1s[t] = fmaxf(h1p[0][t] + h1p[1][t] + h1p[2][t] + h1p[3][t] + b1[t], 0.f);
  __syncthreads();
  {
    int n = t & 63, s = t >> 6;
    int k0 = s * 16;
    float acc = 0.f;
#pragma unroll
    for (int k = 0; k < 16; ++k) acc = fmaf(h1s[k0 + k], W2[(size_t)(k0 + k) * 64 + n], acc);
    h2p[s][n] = acc;
  }
  __syncthreads();
  if (t < 64) {
    float a = h2p[0][t];
#pragma unroll
    for (int s = 1; s < 8; ++s) a += h2p[s][t];
    h2s[t] = fmaxf(a + b2[t], 0.f);
  }
  __syncthreads();
  if (t < 5) {
    float a = b3[t];
    for (int k = 0; k < 64; ++k) a = fmaf(h2s[k], W3[k * 5 + t], a);
    lg[t] = a;
  }
  __syncthreads();
  if (t == 0) {
    double p2 = 0.0;
    for (int i = 0; i < 8; ++i) p2 += redd[i];
    double m = lg[0];
    for (int i = 1; i < 5; ++i) m = fmax(m, (double)lg[i]);
    double se = 0.0, cv = 0.0;
    for (int i = 0; i < 5; ++i) { double e = exp((double)lg[i] - m); se += e; cv += e * 0.2 * (double)(i + 1); }
    double c = cv / se;
    ws[OFF_C + w] = (float)c;
    double sc = sqrt(c);
    double ntrue = sqrt(p2);
    double nf = fmax(ntrue, 1e-5);
    double th = tanh(sc * nf);
    double s0 = th / (sc * nf);
    double ny = fmax(s0 * ntrue, 1e-5);
    double mx = 0.999 / sc;
    if (ny > mx) s0 *= mx / ny;
    sBeta = s0;
    ((double*)(ws + OFF_X2D))[w] = s0 * s0 * p2;
  }
  __syncthreads();
  float beta = (float)sBeta;
  for (int d = t; d < DIM; d += 512) ws[OFF_XVEC + w * DIM + d] = beta * pr[d];
}

// split-K GEMM into G via atomics; dotail: last block per q-tile writes final output
__global__ __launch_bounds__(256) void k_gemm(const float* __restrict__ X, const float* __restrict__ Qm,
                                              float* ws, int dotail, float* __restrict__ out) {
  __shared__ float qs[64][132];
  __shared__ float xs[64][36];
  __shared__ int tailflag;
  float* G = ws + OFF_G;
  int q0 = blockIdx.x * 128, k0 = blockIdx.y * 64;
  int t = threadIdx.x;
  {
    int kk = t & 15, qb = t >> 4;
#pragma unroll
    for (int p = 0; p < 8; ++p) {
      int q = p * 16 + qb;
      const float4 v = *(const float4*)(Qm + (size_t)(q0 + q) * DIM + k0 + kk * 4);
      qs[kk * 4 + 0][q] = v.x; qs[kk * 4 + 1][q] = v.y; qs[kk * 4 + 2][q] = v.z; qs[kk * 4 + 3][q] = v.w;
    }
#pragma unroll
    for (int p = 0; p < 2; ++p) {
      int fi = p * 256 + t;
      int xw = fi >> 4, kk2 = fi & 15;
      const float4 v = *(const float4*)(X + (size_t)xw * DIM + k0 + kk2 * 4);
      xs[kk2 * 4 + 0][xw] = v.x; xs[kk2 * 4 + 1][xw] = v.y; xs[kk2 * 4 + 2][xw] = v.z; xs[kk2 * 4 + 3][xw] = v.w;
    }
  }
  __syncthreads();
  int qg = t & 31, wg = t >> 5;
  float acc[4][4] = {};
#pragma unroll 8
  for (int k = 0; k < 64; ++k) {
    float4 qv = *(const float4*)&qs[k][qg * 4];
    float4 xv = *(const float4*)&xs[k][wg * 4];
    acc[0][0] = fmaf(xv.x, qv.x, acc[0][0]); acc[0][1] = fmaf(xv.x, qv.y, acc[0][1]);
    acc[0][2] = fmaf(xv.x, qv.z, acc[0][2]); acc[0][3] = fmaf(xv.x, qv.w, acc[0][3]);
    acc[1][0] = fmaf(xv.y, qv.x, acc[1][0]); acc[1][1] = fmaf(xv.y, qv.y, acc[1][1]);
    acc[1][2] = fmaf(xv.y, qv.z, acc[1][2]); acc[1][3] = fmaf(xv.y, qv.w, acc[1][3]);
    acc[2][0] = fmaf(xv.z, qv.x, acc[2][0]); acc[2][1] = fmaf(xv.z, qv.y, acc[2][1]);
    acc[2][2] = fmaf(xv.z, qv.z, acc[2][2]); acc[2][3] = fmaf(xv.z, qv.w, acc[2][3]);
    acc[3][0] = fmaf(xv.w, qv.x, acc[3][0]); acc[3][1] = fmaf(xv.w, qv.y, acc[3][1]);
    acc[3][2] = fmaf(xv.w, qv.z, acc[3][2]); acc[3][3] = fmaf(xv.w, qv.w, acc[3][3]);
  }
  int wb = wg * 4, qb2 = q0 + qg * 4;
#pragma unroll
  for (int i = 0; i < 4; ++i)
#pragma unroll
    for (int j = 0; j < 4; ++j)
      atomicAdd(&G[(size_t)(wb + i) * NQ + qb2 + j], acc[i][j]);

  if (dotail) {
    __threadfence();
    __syncthreads();
    if (t == 0) {
      int old = atomicAdd(((int*)(ws + OFF_CNT)) + blockIdx.x, 1);
      tailflag = (old == 9);
    }
    __syncthreads();
    if (tailflag) {
      __threadfence();
      const double* q2d = (const double*)(ws + OFF_Q2D);
      const double* x2d2 = (const double*)(ws + OFF_X2D2);
#pragma unroll
      for (int i = 0; i < 16; ++i) {
        int idx = t * 16 + i;
        int w = idx & 31, ql = idx >> 5;
        int q = q0 + ql;
        float g = __hip_atomic_load(&G[(size_t)w * NQ + q], __ATOMIC_RELAXED, __HIP_MEMORY_SCOPE_AGENT);
        double d = dist_hyp((double)ws[OFF_C + w], (double)g, x2d2[w], q2d[q]);
        out[(size_t)q * WAY + w] = (float)(-d / 16.0);
      }
    }
  }
}

// per-way: inline dist from G, row sum S, first-10-raw-col sum U, stable top-10
__global__ __launch_bounds__(1024) void k_topk(float* ws, int* nidx) {
  __shared__ double sredS[16], sredU[16];
  __shared__ float wv[16]; __shared__ int wi[16];
  __shared__ int swi;
  int w = blockIdx.x, t = threadIdx.x;
  int lane = t & 63, wid = t >> 6;
  const double* q2d = (const double*)(ws + OFF_Q2D);
  const double* x2d = (const double*)(ws + OFF_X2D);
  double c = (double)ws[OFF_C + w];
  double u2 = x2d[w];
  const float* gb = ws + OFF_G + (size_t)w * NQ;
  float v0 = (float)dist_hyp(c, (double)gb[t],        u2, q2d[t]);
  float v1 = (float)dist_hyp(c, (double)gb[1024 + t], u2, q2d[1024 + t]);
  float v2 = (float)dist_hyp(c, (double)gb[2048 + t], u2, q2d[2048 + t]);
  float v3 = (float)dist_hyp(c, (double)gb[3072 + t], u2, q2d[3072 + t]);
  unsigned tk = 0;
  double s = (double)v0 + (double)v1 + (double)v2 + (double)v3;
  double u = (t < RNEAR) ? (double)v0 : 0.0;
  s = wave_sum_d(s);
  u = wave_sum_d(u);
  if (lane == 0) { sredS[wid] = s; sredU[wid] = u; }
  __syncthreads();
  if (t == 0) {
    double S = 0.0, U = 0.0;
    for (int k = 0; k < 16; ++k) { S += sredS[k]; U += sredU[k]; }
    ws[OFF_S + w] = (float)S;
    ws[OFF_U + w] = (float)U;
  }
  for (int r = 0; r < RNEAR; ++r) {
    float lv = INFINITY; int li = 0x7fffffff;
    if (!(tk & 1u) && (v0 < lv || (v0 == lv && t < li)))        { lv = v0; li = t; }
    if (!(tk & 2u) && (v1 < lv || (v1 == lv && 1024 + t < li))) { lv = v1; li = 1024 + t; }
    if (!(tk & 4u) && (v2 < lv || (v2 == lv && 2048 + t < li))) { lv = v2; li = 2048 + t; }
    if (!(tk & 8u) && (v3 < lv || (v3 == lv && 3072 + t < li))) { lv = v3; li = 3072 + t; }
#pragma unroll
    for (int o = 32; o > 0; o >>= 1) {
      float ov = __shfl_down(lv, o, 64);
      int oi = __shfl_down(li, o, 64);
      if (ov < lv || (ov == lv && oi < li)) { lv = ov; li = oi; }
    }
    if (lane == 0) { wv[wid] = lv; wi[wid] = li; }
    __syncthreads();
    if (t < 64) {
      float bv = (lane < 16) ? wv[lane] : INFINITY;
      int bi = (lane < 16) ? wi[lane] : 0x7fffffff;
#pragma unroll
      for (int o = 8; o > 0; o >>= 1) {
        float ov = __shfl_down(bv, o, 64);
        int oi = __shfl_down(bi, o, 64);
        if (ov < bv || (ov == bv && oi < bi)) { bv = ov; bi = oi; }
      }
      if (lane == 0) {
        ws[OFF_NID + w * RNEAR + r] = bv;
        nidx[w * RNEAR + r] = bi;
        swi = bi;
      }
    }
    __syncthreads();
    int sw = swi;
    if ((sw & 1023) == t) tk |= 1u << (sw >> 10);
  }
}

// fused: per-way stats (dists recomputed from G) + refine MLP + tmp/expmap -> TP; zero G+cnt for gemm2
__global__ __launch_bounds__(512) void k_reftmp(const float* __restrict__ Qm,
                                                const float* __restrict__ Wr1, const float* __restrict__ br1,
                                                const float* __restrict__ Wr2, const float* __restrict__ br2,
                                                float* ws, const int* __restrict__ nidx) {
  __shared__ float colsh[RNEAR][33];
  __shared__ float rr[22];
  __shared__ float qjNid[RNEAR];
  __shared__ int qj[RNEAR];
  __shared__ float Ssh[WAY], Ush[WAY], csh[WAY];
  __shared__ double x2sh[WAY];
  __shared__ float hr[RNEAR], iw[RNEAR];
  __shared__ float onw_sh;
  __shared__ double p2red[8];
  __shared__ double gshd;
  int w = blockIdx.x, t = threadIdx.x;
  int lane = t & 63, wid = t >> 6;
  const double* q2d = (const double*)(ws + OFF_Q2D);
  if (t < WAY) {
    Ssh[t] = ws[OFF_S + t]; Ush[t] = ws[OFF_U + t];
    csh[t] = ws[OFF_C + t]; x2sh[t] = ((const double*)(ws + OFF_X2D))[t];
  }
  if (t >= 64 && t < 64 + RNEAR) {
    int j = t - 64;
    qj[j] = nidx[w * RNEAR + j];
    qjNid[j] = ws[OFF_NID + w * RNEAR + j];
  }
  __syncthreads();
  if (t < WAY * RNEAR) {
    int j = t >> 5, w2 = t & 31;
    int q = qj[j];
    float dv = (float)dist_hyp((double)csh[w2], (double)ws[OFF_G + (size_t)w2 * NQ + q], x2sh[w2], q2d[q]);
    colsh[j][w2] = dv;
  }
  __syncthreads();
  if (t < RNEAR) {
    double cs = 0.0, pc = 0.0;
    for (int w2 = 0; w2 < WAY; ++w2) {
      float dv = colsh[t][w2];
      cs += dv;
      if (w2 < w) pc += dv;
    }
    rr[t] = qjNid[t];
    rr[RNEAR + t] = (float)((cs - qjNid[t]) / (double)(WAY - 1));
    colsh[t][32] = (float)pc;
  }
  __syncthreads();
  if (t == 0) {
    double sn = 0.0; for (int j = 0; j < RNEAR; ++j) sn += rr[j];
    double oi = ((double)Ssh[w] - sn) / (double)(NQ - RNEAR);
    double pref = 0.0; for (int j = 0; j < w; ++j) pref += Ssh[j];
    double suf = 0.0; for (int j = w + 1; j < WAY; ++j) suf += (double)Ssh[j] - (double)Ush[j];
    double spc = 0.0; for (int j = 0; j < RNEAR; ++j) spc += colsh[j][32];
    rr[20] = (float)oi;
    rr[21] = (float)((pref - spc + suf) / ((double)(WAY - 1) * (double)(NQ - RNEAR)));
  }
  __syncthreads();
  if (t < RNEAR) {
    float a = br1[t];
    for (int k = 0; k < 22; ++k) a = fmaf(rr[k], Wr1[k * RNEAR + t], a);
    hr[t] = fmaxf(a, 0.f);
  }
  __syncthreads();
  if (t == 0) {
    double o[11];
    for (int r2 = 0; r2 < 11; ++r2) {
      float a = br2[r2];
      for (int k = 0; k < RNEAR; ++k) a = fmaf(hr[k], Wr2[k * 11 + r2], a);
      o[r2] = a;
    }
    double m = o[0]; for (int i = 1; i < RNEAR; ++i) m = fmax(m, o[i]);
    double se = 0.0; double e[RNEAR];
    for (int i = 0; i < RNEAR; ++i) { e[i] = exp(o[i] - m); se += e[i]; }
    for (int i = 0; i < RNEAR; ++i) iw[i] = (float)(e[i] / se);
    onw_sh = (float)(1.0 / (1.0 + exp(-o[10])));
  }
  __syncthreads();
  float onwv = onw_sh;
  float a0 = 0.f, a1 = 0.f;
  bool has2 = (t + 512 < DIM);   // t < 128
  double ls = 0.0;
  {
    int d = t;
    float wd = 0.f;
#pragma unroll
    for (int j = 0; j < RNEAR; ++j) wd = fmaf(Qm[(size_t)qj[j] * DIM + d], iw[j], wd);
    a0 = ws[OFF_PROTOS + w * DIM + d] * onwv + wd * (1.f - onwv);
    ls += (double)a0 * a0;
  }
  if (has2) {
    int d = t + 512;
    float wd = 0.f;
#pragma unroll
    for (int j = 0; j < RNEAR; ++j) wd = fmaf(Qm[(size_t)qj[j] * DIM + d], iw[j], wd);
    a1 = ws[OFF_PROTOS + w * DIM + d] * onwv + wd * (1.f - onwv);
    ls += (double)a1 * a1;
  }
  ls = wave_sum_d(ls);
  if (lane == 0) p2red[wid] = ls;
  __syncthreads();
  if (t == 0) {
    double p2 = 0.0;
    for (int i = 0; i < 8; ++i) p2 += p2red[i];
    double c = (double)csh[w];
    double sc = sqrt(c);
    double ntrue = sqrt(p2);
    double nf = fmax(ntrue, 1e-5);
    double th = tanh(sc * nf);
    double s0 = th / (sc * nf);
    double ny = fmax(s0 * ntrue, 1e-5);
    double mx = 0.999 / sc;
    if (ny > mx) s0 *= mx / ny;
    gshd = s0;
    ((double*)(ws + OFF_X2D2))[w] = s0 * s0 * p2;
  }
  __syncthreads();
  float g = (float)gshd;
  ws[OFF_TP + w * DIM + t] = g * a0;
  if (has2) ws[OFF_TP + w * DIM + t + 512] = g * a1;
  // zero G + counters for gemm2
  for (int j = w * 512 + t; j < WAY * NQ; j += WAY * 512) ws[OFF_G + j] = 0.0f;
  if (t == 0) ((int*)(ws + OFF_CNT))[w] = 0;
}

extern "C" void kernel_launch(void* const* d_in, const int* in_sizes, int n_in,
                              void* d_out, int out_size, void* d_ws, size_t ws_size,
                              hipStream_t stream) {
  (void)in_sizes; (void)n_in; (void)out_size; (void)ws_size;
  const float* shot = (const float*)d_in[0];
  const float* qry  = (const float*)d_in[1];
  const float* W1   = (const float*)d_in[2];
  const float* b1   = (const float*)d_in[3];
  const float* W2   = (const float*)d_in[4];
  const float* b2   = (const float*)d_in[5];
  const float* W3   = (const float*)d_in[6];
  const float* b3   = (const float*)d_in[7];
  const float* Wr1  = (const float*)d_in[8];
  const float* br1  = (const float*)d_in[9];
  const float* Wr2  = (const float*)d_in[10];
  const float* br2  = (const float*)d_in[11];
  float* ws = (float*)d_ws;
  float* out = (float*)d_out;
  int* nidx = (int*)(ws + OFF_NIDX);

  hipLaunchKernelGGL(k_fuse1,  dim3(128), dim3(640), 0, stream, qry, shot, ws);
  hipLaunchKernelGGL(k_ctrl,   dim3(32), dim3(512), 0, stream, W1, b1, W2, b2, W3, b3, ws);
  hipLaunchKernelGGL(k_gemm,   dim3(32, 10), dim3(256), 0, stream, ws + OFF_XVEC, qry, ws, 0, out);
  hipLaunchKernelGGL(k_topk,   dim3(32), dim3(1024), 0, stream, ws, nidx);
  hipLaunchKernelGGL(k_reftmp, dim3(32), dim3(512), 0, stream, qry, Wr1, br1, Wr2, br2, ws, nidx);
  hipLaunchKernelGGL(k_gemm,   dim3(32, 10), dim3(256), 0, stream, ws + OFF_TP, qry, ws, 1, out);
}

// Round 6
// 107.230 us; speedup vs baseline: 1.5323x; 1.5323x over previous
//
#include <hip/hip_runtime.h>
#include <math.h>

#define NSHOT 5
#define WAY 32
#define DIM 640
#define NQ 4096
#define RNEAR 10

// ---- workspace layout (float offsets) ----
constexpr int OFF_PROTOS = 0;        // 32*640
constexpr int OFF_QPART  = 20480;    // 128*640 column partial sums
constexpr int OFF_C      = 102400;   // 32
constexpr int OFF_XVEC   = 102432;   // 32*640 (proto_p)
constexpr int OFF_DIS    = 122912;   // 32*4096 distances
constexpr int OFF_S      = 253984;   // 32
constexpr int OFF_U      = 254016;   // 32
constexpr int OFF_NID    = 254048;   // 32*10
constexpr int OFF_TP     = 254368;   // 32*640 (test_proto)
constexpr int OFF_NIDX   = 274848;   // 32*10 ints
constexpr int OFF_Q2D    = 275200;   // double[4096]
constexpr int OFF_X2D    = 283392;   // double[32]  (proto_p norms^2)
constexpr int OFF_X2D2   = 283456;   // double[32]  (test_proto norms^2)

__device__ __forceinline__ double wave_sum_d(double v) {
#pragma unroll
  for (int o = 32; o > 0; o >>= 1) v += __shfl_down(v, o, 64);
  return v;
}

__device__ __forceinline__ double dist_hyp(double c, double xdotq, double u2, double q2) {
  const double EPSd = 1e-5;
  double sc = sqrt(c);
  double nq = sqrt(q2);
  double nf = fmax(nq, EPSd);
  double th = tanh(sc * nf);
  double al = th / (sc * nf);
  double ny = fmax(al * nq, EPSd);
  double mx = 0.999 / sc;
  if (ny > mx) al *= mx / ny;
  double y2 = al * al * q2;
  double uy = -al * xdotq;
  double A = 1.0 + 2.0 * c * uy + c * y2;
  double B = 1.0 - c * u2;
  double den = fmax(1.0 + 2.0 * c * uy + c * c * u2 * y2, EPSd);
  double num2 = fmax(A * A * u2 + 2.0 * A * B * uy + B * B * y2, 0.0);
  double n = sqrt(num2) / den;
  double arg = sc * n;
  const double CLIP = (double)(1.0f - 1e-5f);
  arg = fmin(fmax(arg, 0.0), CLIP);
  return (1.0 / sc) * log((1.0 + arg) / (1.0 - arg));
}

// one pass over Q: per-row q2 (f64), per-block column partial sums, protos
__global__ __launch_bounds__(640) void k_fuse1(const float* __restrict__ Qm,
                                               const float* __restrict__ shot, float* ws) {
  __shared__ double q2w[32][10];
  int b = blockIdx.x, t = threadIdx.x;
  int lane = t & 63, wid = t >> 6;  // 10 waves
  if (b < WAY) {
    float s = 0.f;
#pragma unroll
    for (int s5 = 0; s5 < NSHOT; ++s5) s += shot[(size_t)(s5 * WAY + b) * DIM + t];
    ws[OFF_PROTOS + b * DIM + t] = s * 0.2f;
  }
  int r0 = b * 32;
  float colacc = 0.f;
  for (int r = 0; r < 32; ++r) {
    float v = Qm[(size_t)(r0 + r) * DIM + t];
    colacc += v;
    double sq = (double)v * v;
    sq = wave_sum_d(sq);
    if (lane == 0) q2w[r][wid] = sq;
  }
  ws[OFF_QPART + b * DIM + t] = colacc;
  __syncthreads();
  if (t < 32) {
    double s = 0.0;
#pragma unroll
    for (int k = 0; k < 10; ++k) s += q2w[t][k];
    ((double*)(ws + OFF_Q2D))[r0 + t] = s;
  }
}

// controller MLP, split-K, 512 threads; allmean from qpart partials inline
__global__ __launch_bounds__(512) void k_ctrl(const float* __restrict__ W1, const float* __restrict__ b1,
                                              const float* __restrict__ W2, const float* __restrict__ b2,
                                              const float* __restrict__ W3, const float* __restrict__ b3,
                                              float* ws) {
  __shared__ float pr[DIM], am[DIM];
  __shared__ float h1p[4][128], h1s[128];
  __shared__ float h2p[8][64], h2s[64];
  __shared__ float lg[5];
  __shared__ double redd[8];
  __shared__ double sBeta;
  int w = blockIdx.x, t = threadIdx.x;
  double ps = 0.0;
  for (int d = t; d < DIM; d += 512) {
    float v = ws[OFF_PROTOS + w * DIM + d];
    pr[d] = v; ps += (double)v * v;
    float qs_ = 0.f;
    for (int p = 0; p < 128; ++p) qs_ += ws[OFF_QPART + p * DIM + d];
    double s = (double)qs_;
    for (int w2 = 0; w2 < WAY; ++w2) s += 5.0 * (double)ws[OFF_PROTOS + w2 * DIM + d];
    am[d] = (float)(s / 4256.0);
  }
  ps = wave_sum_d(ps);
  int lane = t & 63, wid = t >> 6;
  if (lane == 0) redd[wid] = ps;
  __syncthreads();
  {
    int n = t & 127, s = t >> 7;
    float acc = 0.f;
    if (s < 2) {
      int k0 = s * 320;
#pragma unroll 8
      for (int k = 0; k < 320; ++k) acc = fmaf(pr[k0 + k], W1[(size_t)(k0 + k) * 128 + n], acc);
    } else {
      int k0 = (s - 2) * 320;
#pragma unroll 8
      for (int k = 0; k < 320; ++k) acc = fmaf(am[k0 + k], W1[(size_t)(640 + k0 + k) * 128 + n], acc);
    }
    h1p[s][n] = acc;
  }
  __syncthreads();
  if (t < 128) h1s[t] = fmaxf(h1p[0][t] + h1p[1][t] + h1p[2][t] + h1p[3][t] + b1[t], 0.f);
  __syncthreads();
  {
    int n = t & 63, s = t >> 6;
    int k0 = s * 16;
    float acc = 0.f;
#pragma unroll
    for (int k = 0; k < 16; ++k) acc = fmaf(h1s[k0 + k], W2[(size_t)(k0 + k) * 64 + n], acc);
    h2p[s][n] = acc;
  }
  __syncthreads();
  if (t < 64) {
    float a = h2p[0][t];
#pragma unroll
    for (int s = 1; s < 8; ++s) a += h2p[s][t];
    h2s[t] = fmaxf(a + b2[t], 0.f);
  }
  __syncthreads();
  if (t < 5) {
    float a = b3[t];
    for (int k = 0; k < 64; ++k) a = fmaf(h2s[k], W3[k * 5 + t], a);
    lg[t] = a;
  }
  __syncthreads();
  if (t == 0) {
    double p2 = 0.0;
    for (int i = 0; i < 8; ++i) p2 += redd[i];
    double m = lg[0];
    for (int i = 1; i < 5; ++i) m = fmax(m, (double)lg[i]);
    double se = 0.0, cv = 0.0;
    for (int i = 0; i < 5; ++i) { double e = exp((double)lg[i] - m); se += e; cv += e * 0.2 * (double)(i + 1); }
    double c = cv / se;
    ws[OFF_C + w] = (float)c;
    double sc = sqrt(c);
    double ntrue = sqrt(p2);
    double nf = fmax(ntrue, 1e-5);
    double th = tanh(sc * nf);
    double s0 = th / (sc * nf);
    double ny = fmax(s0 * ntrue, 1e-5);
    double mx = 0.999 / sc;
    if (ny > mx) s0 *= mx / ny;
    sBeta = s0;
    ((double*)(ws + OFF_X2D))[w] = s0 * s0 * p2;
  }
  __syncthreads();
  float beta = (float)sBeta;
  for (int d = t; d < DIM; d += 512) ws[OFF_XVEC + w * DIM + d] = beta * pr[d];
}

// full-K GEMM tile + fused distance epilogue. grid 256 (16 q each), 256 threads.
// thread (q = t&15, wp = t>>4) owns outputs (wp, q0+q) and (wp+16, q0+q).
// mode 0: write DIS[w][q]; mode 1: write out[q][w] = -d/16.
__global__ __launch_bounds__(256) void k_gemmdist(const float* __restrict__ X, const float* __restrict__ Qm,
                                                  float* __restrict__ ws, int mode, float* __restrict__ out) {
  __shared__ float Qs[2][16][68];
  __shared__ float Xs[2][32][68];
  int t = threadIdx.x;
  int q = t & 15, wp = t >> 4;
  int q0 = blockIdx.x * 16;
  int colbase = (t & 15) * 4;
  int rq = t >> 4;  // staging row 0..15
  const float* qsrc  = Qm + (size_t)(q0 + rq) * DIM + colbase;
  const float* x0src = X + (size_t)rq * DIM + colbase;
  const float* x1src = X + (size_t)(16 + rq) * DIM + colbase;
  float4 qreg  = *(const float4*)(qsrc);
  float4 x0reg = *(const float4*)(x0src);
  float4 x1reg = *(const float4*)(x1src);
  *(float4*)&Qs[0][rq][colbase] = qreg;
  *(float4*)&Xs[0][rq][colbase] = x0reg;
  *(float4*)&Xs[0][16 + rq][colbase] = x1reg;
  __syncthreads();
  float acc0 = 0.f, acc1 = 0.f;
  for (int c = 0; c < 10; ++c) {
    int b = c & 1;
    if (c < 9) {                       // issue next-chunk loads early (hide latency under FMA)
      int kc = (c + 1) * 64;
      qreg  = *(const float4*)(qsrc + kc);
      x0reg = *(const float4*)(x0src + kc);
      x1reg = *(const float4*)(x1src + kc);
    }
    const float* qrow = &Qs[b][q][0];
    const float* xr0  = &Xs[b][wp][0];
    const float* xr1  = &Xs[b][wp + 16][0];
#pragma unroll
    for (int kk = 0; kk < 64; kk += 4) {
      float4 qv = *(const float4*)(qrow + kk);
      float4 a  = *(const float4*)(xr0 + kk);
      float4 bb = *(const float4*)(xr1 + kk);
      acc0 = fmaf(a.x, qv.x, acc0);  acc0 = fmaf(a.y, qv.y, acc0);
      acc0 = fmaf(a.z, qv.z, acc0);  acc0 = fmaf(a.w, qv.w, acc0);
      acc1 = fmaf(bb.x, qv.x, acc1); acc1 = fmaf(bb.y, qv.y, acc1);
      acc1 = fmaf(bb.z, qv.z, acc1); acc1 = fmaf(bb.w, qv.w, acc1);
    }
    if (c < 9) {
      __syncthreads();
      int nb = b ^ 1;
      *(float4*)&Qs[nb][rq][colbase] = qreg;
      *(float4*)&Xs[nb][rq][colbase] = x0reg;
      *(float4*)&Xs[nb][16 + rq][colbase] = x1reg;
      __syncthreads();
    }
  }
  // fused distance epilogue
  const double* q2d   = (const double*)(ws + OFF_Q2D);
  const double* u2arr = (const double*)(ws + (mode ? OFF_X2D2 : OFF_X2D));
  int qq = q0 + q;
  double q2 = q2d[qq];
  double d0 = dist_hyp((double)ws[OFF_C + wp],      (double)acc0, u2arr[wp],      q2);
  double d1 = dist_hyp((double)ws[OFF_C + wp + 16], (double)acc1, u2arr[wp + 16], q2);
  if (mode == 0) {
    ws[OFF_DIS + (size_t)wp * NQ + qq]        = (float)d0;
    ws[OFF_DIS + (size_t)(wp + 16) * NQ + qq] = (float)d1;
  } else {
    out[(size_t)qq * WAY + wp]      = (float)(-d0 / 16.0);
    out[(size_t)qq * WAY + wp + 16] = (float)(-d1 / 16.0);
  }
}

// per-way: row sum S, first-10-raw-col sum U, stable top-10 (value, then index).
// All per-thread state in registers (4 named values + 4-bit taken mask). 1024 threads.
__global__ __launch_bounds__(1024) void k_topk(float* ws, int* nidx) {
  __shared__ double sredS[16], sredU[16];
  __shared__ float wv[16]; __shared__ int wi[16];
  __shared__ int swi;
  int w = blockIdx.x, t = threadIdx.x;
  int lane = t & 63, wid = t >> 6;
  const float* base = ws + OFF_DIS + (size_t)w * NQ;
  float v0 = base[t], v1 = base[1024 + t], v2 = base[2048 + t], v3 = base[3072 + t];
  unsigned tk = 0;
  double s = (double)v0 + (double)v1 + (double)v2 + (double)v3;
  double u = (t < RNEAR) ? (double)v0 : 0.0;
  s = wave_sum_d(s);
  u = wave_sum_d(u);
  if (lane == 0) { sredS[wid] = s; sredU[wid] = u; }
  __syncthreads();
  if (t == 0) {
    double S = 0.0, U = 0.0;
    for (int k = 0; k < 16; ++k) { S += sredS[k]; U += sredU[k]; }
    ws[OFF_S + w] = (float)S;
    ws[OFF_U + w] = (float)U;
  }
  for (int r = 0; r < RNEAR; ++r) {
    float lv = INFINITY; int li = 0x7fffffff;
    if (!(tk & 1u) && (v0 < lv || (v0 == lv && t < li)))        { lv = v0; li = t; }
    if (!(tk & 2u) && (v1 < lv || (v1 == lv && 1024 + t < li))) { lv = v1; li = 1024 + t; }
    if (!(tk & 4u) && (v2 < lv || (v2 == lv && 2048 + t < li))) { lv = v2; li = 2048 + t; }
    if (!(tk & 8u) && (v3 < lv || (v3 == lv && 3072 + t < li))) { lv = v3; li = 3072 + t; }
#pragma unroll
    for (int o = 32; o > 0; o >>= 1) {
      float ov = __shfl_down(lv, o, 64);
      int oi = __shfl_down(li, o, 64);
      if (ov < lv || (ov == lv && oi < li)) { lv = ov; li = oi; }
    }
    if (lane == 0) { wv[wid] = lv; wi[wid] = li; }
    __syncthreads();
    if (t < 64) {
      float bv = (lane < 16) ? wv[lane] : INFINITY;
      int bi = (lane < 16) ? wi[lane] : 0x7fffffff;
#pragma unroll
      for (int o = 8; o > 0; o >>= 1) {
        float ov = __shfl_down(bv, o, 64);
        int oi = __shfl_down(bi, o, 64);
        if (ov < bv || (ov == bv && oi < bi)) { bv = ov; bi = oi; }
      }
      if (lane == 0) {
        ws[OFF_NID + w * RNEAR + r] = bv;
        nidx[w * RNEAR + r] = bi;
        swi = bi;
      }
    }
    __syncthreads();
    int sw = swi;
    if ((sw & 1023) == t) tk |= 1u << (sw >> 10);
  }
}

// fused: per-way stats (cols read from DIS) + refine MLP + tmp/expmap -> TP
__global__ __launch_bounds__(512) void k_reftmp(const float* __restrict__ Qm,
                                                const float* __restrict__ Wr1, const float* __restrict__ br1,
                                                const float* __restrict__ Wr2, const float* __restrict__ br2,
                                                float* ws, const int* __restrict__ nidx) {
  __shared__ float colsh[RNEAR][33];
  __shared__ float rr[22];
  __shared__ float qjNid[RNEAR];
  __shared__ int qj[RNEAR];
  __shared__ float Ssh[WAY], Ush[WAY];
  __shared__ float hr[RNEAR], iw[RNEAR];
  __shared__ float onw_sh;
  __shared__ double p2red[8];
  __shared__ double gshd;
  int w = blockIdx.x, t = threadIdx.x;
  int lane = t & 63, wid = t >> 6;
  if (t < WAY) { Ssh[t] = ws[OFF_S + t]; Ush[t] = ws[OFF_U + t]; }
  if (t >= 64 && t < 64 + RNEAR) {
    int j = t - 64;
    qj[j] = nidx[w * RNEAR + j];
    qjNid[j] = ws[OFF_NID + w * RNEAR + j];
  }
  __syncthreads();
  if (t < WAY * RNEAR) {
    int j = t >> 5, w2 = t & 31;
    colsh[j][w2] = ws[OFF_DIS + (size_t)w2 * NQ + qj[j]];
  }
  __syncthreads();
  if (t < RNEAR) {
    double cs = 0.0, pc = 0.0;
    for (int w2 = 0; w2 < WAY; ++w2) {
      float dv = colsh[t][w2];
      cs += dv;
      if (w2 < w) pc += dv;
    }
    rr[t] = qjNid[t];
    rr[RNEAR + t] = (float)((cs - qjNid[t]) / (double)(WAY - 1));
    colsh[t][32] = (float)pc;
  }
  __syncthreads();
  if (t == 0) {
    double sn = 0.0; for (int j = 0; j < RNEAR; ++j) sn += rr[j];
    double oi = ((double)Ssh[w] - sn) / (double)(NQ - RNEAR);
    double pref = 0.0; for (int j = 0; j < w; ++j) pref += Ssh[j];
    double suf = 0.0; for (int j = w + 1; j < WAY; ++j) suf += (double)Ssh[j] - (double)Ush[j];
    double spc = 0.0; for (int j = 0; j < RNEAR; ++j) spc += colsh[j][32];
    rr[20] = (float)oi;
    rr[21] = (float)((pref - spc + suf) / ((double)(WAY - 1) * (double)(NQ - RNEAR)));
  }
  __syncthreads();
  if (t < RNEAR) {
    float a = br1[t];
    for (int k = 0; k < 22; ++k) a = fmaf(rr[k], Wr1[k * RNEAR + t], a);
    hr[t] = fmaxf(a, 0.f);
  }
  __syncthreads();
  if (t == 0) {
    double o[11];
    for (int r2 = 0; r2 < 11; ++r2) {
      float a = br2[r2];
      for (int k = 0; k < RNEAR; ++k) a = fmaf(hr[k], Wr2[k * 11 + r2], a);
      o[r2] = a;
    }
    double m = o[0]; for (int i = 1; i < RNEAR; ++i) m = fmax(m, o[i]);
    double se = 0.0; double e[RNEAR];
    for (int i = 0; i < RNEAR; ++i) { e[i] = exp(o[i] - m); se += e[i]; }
    for (int i = 0; i < RNEAR; ++i) iw[i] = (float)(e[i] / se);
    onw_sh = (float)(1.0 / (1.0 + exp(-o[10])));
  }
  __syncthreads();
  float onwv = onw_sh;
  float a0 = 0.f, a1 = 0.f;
  bool has2 = (t + 512 < DIM);   // t < 128
  double ls = 0.0;
  {
    int d = t;
    float wd = 0.f;
#pragma unroll
    for (int j = 0; j < RNEAR; ++j) wd = fmaf(Qm[(size_t)qj[j] * DIM + d], iw[j], wd);
    a0 = ws[OFF_PROTOS + w * DIM + d] * onwv + wd * (1.f - onwv);
    ls += (double)a0 * a0;
  }
  if (has2) {
    int d = t + 512;
    float wd = 0.f;
#pragma unroll
    for (int j = 0; j < RNEAR; ++j) wd = fmaf(Qm[(size_t)qj[j] * DIM + d], iw[j], wd);
    a1 = ws[OFF_PROTOS + w * DIM + d] * onwv + wd * (1.f - onwv);
    ls += (double)a1 * a1;
  }
  ls = wave_sum_d(ls);
  if (lane == 0) p2red[wid] = ls;
  __syncthreads();
  if (t == 0) {
    double p2 = 0.0;
    for (int i = 0; i < 8; ++i) p2 += p2red[i];
    double c = (double)ws[OFF_C + w];
    double sc = sqrt(c);
    double ntrue = sqrt(p2);
    double nf = fmax(ntrue, 1e-5);
    double th = tanh(sc * nf);
    double s0 = th / (sc * nf);
    double ny = fmax(s0 * ntrue, 1e-5);
    double mx = 0.999 / sc;
    if (ny > mx) s0 *= mx / ny;
    gshd = s0;
    ((double*)(ws + OFF_X2D2))[w] = s0 * s0 * p2;
  }
  __syncthreads();
  float g = (float)gshd;
  ws[OFF_TP + w * DIM + t] = g * a0;
  if (has2) ws[OFF_TP + w * DIM + t + 512] = g * a1;
}

extern "C" void kernel_launch(void* const* d_in, const int* in_sizes, int n_in,
                              void* d_out, int out_size, void* d_ws, size_t ws_size,
                              hipStream_t stream) {
  (void)in_sizes; (void)n_in; (void)out_size; (void)ws_size;
  const float* shot = (const float*)d_in[0];
  const float* qry  = (const float*)d_in[1];
  const float* W1   = (const float*)d_in[2];
  const float* b1   = (const float*)d_in[3];
  const float* W2   = (const float*)d_in[4];
  const float* b2   = (const float*)d_in[5];
  const float* W3   = (const float*)d_in[6];
  const float* b3   = (const float*)d_in[7];
  const float* Wr1  = (const float*)d_in[8];
  const float* br1  = (const float*)d_in[9];
  const float* Wr2  = (const float*)d_in[10];
  const float* br2  = (const float*)d_in[11];
  float* ws = (float*)d_ws;
  float* out = (float*)d_out;
  int* nidx = (int*)(ws + OFF_NIDX);

  hipLaunchKernelGGL(k_fuse1,    dim3(128), dim3(640), 0, stream, qry, shot, ws);
  hipLaunchKernelGGL(k_ctrl,     dim3(32), dim3(512), 0, stream, W1, b1, W2, b2, W3, b3, ws);
  hipLaunchKernelGGL(k_gemmdist, dim3(256), dim3(256), 0, stream, ws + OFF_XVEC, qry, ws, 0, out);
  hipLaunchKernelGGL(k_topk,     dim3(32), dim3(1024), 0, stream, ws, nidx);
  hipLaunchKernelGGL(k_reftmp,   dim3(32), dim3(512), 0, stream, qry, Wr1, br1, Wr2, br2, ws, nidx);
  hipLaunchKernelGGL(k_gemmdist, dim3(256), dim3(256), 0, stream, ws + OFF_TP, qry, ws, 1, out);
}